// Round 1
// baseline (2072.639 us; speedup 1.0000x reference)
//
#include <hip/hip_runtime.h>
#include <stdint.h>

#define B_  16
#define T_  12
#define N_  2048
#define DE_ 16
#define GH_ 32
#define NH_ 4

typedef __attribute__((ext_vector_type(8)))  short short8;
typedef __attribute__((ext_vector_type(4)))  float f32x4;
typedef __attribute__((ext_vector_type(16))) float f32x16;

__device__ __forceinline__ unsigned short f2b(float f){
  unsigned u = __float_as_uint(f);
  return (unsigned short)((u + 0x7fffu + ((u>>16)&1u)) >> 16);   // RNE
}
__device__ __forceinline__ float b2f(unsigned short h){
  return __uint_as_float(((unsigned)h)<<16);
}
__device__ __forceinline__ unsigned pk2(float a, float b){
  return (unsigned)f2b(a) | ((unsigned)f2b(b)<<16);
}
__device__ __forceinline__ float lrelu(float v){ return v>=0.f ? v : 0.2f*v; }

// async global->LDS, 16B per lane; lds ptr must be wave-uniform
__device__ __forceinline__ void gl16(const void* g, void* l){
  __builtin_amdgcn_global_load_lds((const __attribute__((address_space(1))) void*)g,
                                   (__attribute__((address_space(3))) void*)l, 16, 0, 0);
}

// ---------------- GAT: s,d per (head,node) ----------------
__global__ __launch_bounds__(256) void k_gat_sd(const float* __restrict__ E, const float* __restrict__ gW,
    const float* __restrict__ asrc, const float* __restrict__ adst,
    float* __restrict__ sArr, float* __restrict__ dArr)
{
  int id = blockIdx.x*256 + threadIdx.x;           // 4*2048
  int h = id >> 11, n = id & 2047;
  float hv[GH_];
#pragma unroll
  for (int f=0; f<GH_; ++f) hv[f]=0.f;
  for (int d=0; d<DE_; ++d){
    float e = E[n*DE_+d];
    const float* wr = gW + (h*DE_+d)*GH_;
#pragma unroll
    for (int f=0; f<GH_; ++f) hv[f] += e*wr[f];
  }
  float s=0.f, dd=0.f;
#pragma unroll
  for (int f=0; f<GH_; ++f){ s += hv[f]*asrc[h*GH_+f]; dd += hv[f]*adst[h*GH_+f]; }
  sArr[h*N_+n]=s; dArr[h*N_+n]=dd;
}

__global__ __launch_bounds__(256) void k_dmax(const float* __restrict__ dArr, float* __restrict__ dmax){
  __shared__ float red[256];
  int h = blockIdx.x, t = threadIdx.x;
  float m = -1e30f;
  for (int i=t;i<N_;i+=256) m = fmaxf(m, dArr[h*N_+i]);
  red[t]=m; __syncthreads();
  for (int s=128;s>0;s>>=1){ if (t<s) red[t]=fmaxf(red[t],red[t+s]); __syncthreads(); }
  if (t==0) dmax[h]=red[0];
}

__global__ __launch_bounds__(256) void k_denom(const float* __restrict__ sArr, const float* __restrict__ dArr,
                                               const float* __restrict__ dmax, float* __restrict__ denom){
  __shared__ float red[256];
  int m = blockIdx.x, h = blockIdx.y, t = threadIdx.x;
  float sm = sArr[h*N_+m];
  float shift = lrelu(sm + dmax[h]);
  float acc=0.f;
  for (int i=t;i<N_;i+=256) acc += __expf(lrelu(sm + dArr[h*N_+i]) - shift);
  red[t]=acc; __syncthreads();
  for (int s=128;s>0;s>>=1){ if (t<s) red[t]+=red[t+s]; __syncthreads(); }
  if (t==0) denom[h*N_+m]=red[0];
}

// A[m][n] bf16 row-major = mean_h softmax rows
__global__ __launch_bounds__(256) void k_adj(const float* __restrict__ sArr, const float* __restrict__ dArr,
                                             const float* __restrict__ dmax, const float* __restrict__ denom,
                                             unsigned short* __restrict__ Abf){
  int m = blockIdx.x, t = threadIdx.x;
  float sm[NH_], sh[NH_], inv[NH_];
#pragma unroll
  for (int h=0;h<NH_;++h){ sm[h]=sArr[h*N_+m]; sh[h]=lrelu(sm[h]+dmax[h]); inv[h]=1.f/denom[h*N_+m]; }
  for (int n=t;n<N_;n+=256){
    float acc=0.f;
#pragma unroll
    for (int h=0;h<NH_;++h) acc += __expf(lrelu(sm[h]+dArr[h*N_+n]) - sh[h]) * inv[h];
    Abf[(long)m*N_+n] = f2b(acc*0.25f);
  }
}

// ---------------- NAL weights: W[n][o][kio] bf16, granule-swizzled storage ----------------
// storage flat (per node) f = o*256 + slot*8 + j  holds element kio = ((slot^(o&7))<<3)|j
__global__ __launch_bounds__(256) void k_nalw(const float* __restrict__ E, const float* __restrict__ wp,
                                              unsigned short* __restrict__ Wout, int Osz){
  __shared__ float sS[256][17];
  __shared__ float sE[512*16];
  int o = blockIdx.x, q = blockIdx.y, t = threadIdx.x;
  int slot = t>>3, j = t&7;
  int kio = (((slot ^ (o&7))&31)<<3) | j;
  long dstride = 256L*Osz;                      // wp per-d stride (2*128*Osz)
  for (int d=0; d<DE_; ++d) sS[t][d] = wp[d*dstride + (long)kio*Osz + o];
  for (int i=t; i<512*16; i+=256) sE[i] = E[q*512*16 + i];
  __syncthreads();
  unsigned short* out = Wout + (long)(q*512)*dstride + o*256 + t;
  for (int nn=0; nn<512; ++nn){
    float acc=0.f;
    const float* e = &sE[nn*16];
#pragma unroll
    for (int d=0; d<DE_; ++d) acc += e[d]*sS[t][d];
    out[(long)nn*dstride] = f2b(acc);
  }
}

__global__ __launch_bounds__(256) void k_nalb(const float* __restrict__ E, const float* __restrict__ bpg,
                                              const float* __restrict__ bpc,
                                              unsigned short* __restrict__ bg, unsigned short* __restrict__ bc){
  int id = blockIdx.x*256+threadIdx.x;          // 2048*192
  int n = id/192, oo = id%192;
  float acc=0.f;
  if (oo<128){
    for (int d=0;d<DE_;++d) acc += E[n*DE_+d]*bpg[d*128+oo];
    bg[n*128+oo]=f2b(acc);
  } else {
    int c=oo-128;
    for (int d=0;d<DE_;++d) acc += E[n*DE_+d]*bpc[d*64+c];
    bc[n*64+c]=f2b(acc);
  }
}

// Wcat[o][k] bf16 swizzled: k<192: tc_w[o][k%64][0][k/64]; k>=192: rc_w[o][k-192]
__global__ __launch_bounds__(256) void k_wcat(const float* __restrict__ tcw, const float* __restrict__ rcw,
                                              unsigned short* __restrict__ Wcat){
  int id = blockIdx.x*256+threadIdx.x;          // 16384
  int o = id>>8, k = id&255;
  float v;
  if (k<192){ int dt=k>>6, c=k&63; v = tcw[(o*64+c)*3+dt]; }
  else v = rcw[o*64 + (k&63)];
  int pos = o*256 + ((((k>>3)&31) ^ (o&7))<<3) + (k&7);
  Wcat[pos] = f2b(v);
}

__global__ __launch_bounds__(256) void k_init(const float* __restrict__ init, float* __restrict__ st,
                                              unsigned short* __restrict__ stb){
  int i = blockIdx.x*256+threadIdx.x;
  float v = init[i]; st[i]=v; stb[i]=f2b(v);
}

// ---------------- adjacency GEMM: D[m][j] = sum_k A[m][k]*S[k][j], 64-col descs ----------------
template<int BM, int BN, bool F32SRC>
__global__ __launch_bounds__(256) void k_gemm(
    const unsigned short* __restrict__ Abf,
    const char* __restrict__ S0, long ss0,      // byte stride per z
    const char* __restrict__ S1, long ss1,
    unsigned short* __restrict__ D0, long ds0,  // element stride per z
    unsigned short* __restrict__ D1, long ds1)
{
  constexpr int BK=64;
  constexpr int IA = BM/32;                 // gl16 issues per thread for A tile
  constexpr int WTM = BM/2, WTN = BN/2;
  constexpr int MTC = WTM/32, NTC = WTN/32;
  __shared__ __align__(16) unsigned short sA[BM*BK];
  __shared__ __align__(16) unsigned short sB[BN*BK];
  int tid = threadIdx.x, w = tid>>6, l = tid&63;
  int mB = blockIdx.x, z = blockIdx.y;
  const char* s0 = S0 + (long)z*ss0;
  const char* s1 = (BN==128) ? (S1 + (long)z*ss1) : (const char*)0;
  int wm = w&1, wn = w>>1;
  f32x16 acc[MTC][NTC];
#pragma unroll
  for (int a=0;a<MTC;++a)
#pragma unroll
    for (int b=0;b<NTC;++b)
#pragma unroll
      for (int i=0;i<16;++i) acc[a][b][i]=0.f;

  constexpr int JG = BN/4;
  int jg = tid & (JG-1), kg = tid / JG;
  bool bact = (kg < 8);
  int j0 = jg*4, k0 = kg*8;

  for (int kb=0; kb<2048/BK; ++kb){
    __syncthreads();
    // A tile: linear LDS, pre-swizzled global fetch (logical byte(row,k)=row*128+((k/8 ^ row&7)<<4)+(k&7)*2)
#pragma unroll
    for (int i=0;i<IA;++i){
      int c = (w*IA+i)*64 + l;
      int row = c>>3, slot = c&7;
      int g = slot ^ (row&7);
      gl16((const char*)Abf + (((long)(mB*BM+row))*2048 + kb*BK + g*8)*2,
           (char*)sA + (w*IA+i)*1024);
    }
    // B tile transposed: sB[j][k], same granule swizzle
    if (bact){
      unsigned short vv[8][4];
#pragma unroll
      for (int ii=0; ii<8; ++ii){
        int k = kb*BK + k0 + ii;
        const char* sp; int jj0;
        if (BN==128 && j0>=64){ sp = s1; jj0 = j0-64; } else { sp = s0; jj0 = j0; }
        if (F32SRC){
          const float4 v = *(const float4*)(sp + ((long)k*64 + jj0)*4);
          vv[ii][0]=f2b(v.x); vv[ii][1]=f2b(v.y); vv[ii][2]=f2b(v.z); vv[ii][3]=f2b(v.w);
        } else {
          const ushort4 v = *(const ushort4*)(sp + ((long)k*64 + jj0)*2);
          vv[ii][0]=v.x; vv[ii][1]=v.y; vv[ii][2]=v.z; vv[ii][3]=v.w;
        }
      }
#pragma unroll
      for (int r=0;r<4;++r){
        int jj = j0 + r;
        uint4 pkv;
        pkv.x = (unsigned)vv[0][r] | ((unsigned)vv[1][r]<<16);
        pkv.y = (unsigned)vv[2][r] | ((unsigned)vv[3][r]<<16);
        pkv.z = (unsigned)vv[4][r] | ((unsigned)vv[5][r]<<16);
        pkv.w = (unsigned)vv[6][r] | ((unsigned)vv[7][r]<<16);
        *(uint4*)((char*)sB + jj*128 + ((kg ^ (jj&7))<<4)) = pkv;
      }
    }
    __syncthreads();
#pragma unroll
    for (int ks=0; ks<BK/16; ++ks){
      short8 af[MTC];
#pragma unroll
      for (int mt=0; mt<MTC; ++mt){
        int row = wm*WTM + mt*32 + (l&31);
        int g = ks*2 + (l>>5);
        af[mt] = *(const short8*)((const char*)sA + row*128 + ((g ^ (row&7))<<4));
      }
#pragma unroll
      for (int nt=0; nt<NTC; ++nt){
        int jj = wn*WTN + nt*32 + (l&31);
        int g = ks*2 + (l>>5);
        short8 bfv = *(const short8*)((const char*)sB + jj*128 + ((g ^ (jj&7))<<4));
#pragma unroll
        for (int mt=0; mt<MTC; ++mt)
          acc[mt][nt] = __builtin_amdgcn_mfma_f32_32x32x16_bf16(af[mt], bfv, acc[mt][nt], 0,0,0);
      }
    }
  }
  unsigned short* d0 = D0 + (long)z*ds0;
  unsigned short* d1 = (BN==128) ? (D1 + (long)z*ds1) : (unsigned short*)0;
#pragma unroll
  for (int mt=0; mt<MTC; ++mt)
#pragma unroll
    for (int nt=0; nt<NTC; ++nt)
#pragma unroll
      for (int rg=0; rg<16; ++rg){
        int rl = wm*WTM + mt*32 + (rg&3) + 8*(rg>>2) + 4*(l>>5);
        int col = wn*WTN + nt*32 + (l&31);
        long m = (long)mB*BM + rl;
        unsigned short v = f2b(acc[mt][nt][rg]);
        if (BN==128 && col>=64) d1[m*64 + (col-64)] = v;
        else d0[m*64 + col] = v;
      }
}

// ---------------- gates: zr = sigmoid(xg @ W_g + b_g); z stored, rs = r*state ----------------
__global__ __launch_bounds__(256) void k_gates(
    const float* __restrict__ x, const float* __restrict__ st,
    const unsigned short* __restrict__ AX, const unsigned short* __restrict__ AS,
    const unsigned short* __restrict__ Wg, const unsigned short* __restrict__ bg,
    float* __restrict__ zbuf, unsigned short* __restrict__ rs, int t)
{
  __shared__ __align__(16) unsigned short sW[64*256];
  __shared__ __align__(16) unsigned short sX[16*256];
  int n = blockIdx.x, half = blockIdx.y;
  int tid = threadIdx.x, w = tid>>6, l = tid&63;
  const unsigned short* Wsrc = Wg + (long)n*32768 + half*16384;
#pragma unroll
  for (int i=0;i<8;++i){
    int c = (w*8+i)*64 + l;
    gl16((const char*)Wsrc + c*16, (char*)sW + (w*8+i)*1024);
  }
  int b = tid>>4, c16 = tid&15;
  uint4 g0, g1;
  if (c16 < 8){
    const float* p = (c16<4) ? (x  + (((long)(b*T_+t)*N_ + n)*64 + c16*16))
                             : (st + (((long)b*N_ + n)*64 + (c16-4)*16));
    float4 f0 = *(const float4*)(p+0), f1 = *(const float4*)(p+4);
    float4 f2v = *(const float4*)(p+8), f3 = *(const float4*)(p+12);
    g0.x = pk2(f0.x,f0.y); g0.y = pk2(f0.z,f0.w); g0.z = pk2(f1.x,f1.y); g0.w = pk2(f1.z,f1.w);
    g1.x = pk2(f2v.x,f2v.y); g1.y = pk2(f2v.z,f2v.w); g1.z = pk2(f3.x,f3.y); g1.w = pk2(f3.z,f3.w);
  } else {
    const unsigned short* p = (c16<12) ? (AX + (((long)(b*T_+t)*N_ + n)*64 + (c16-8)*16))
                                       : (AS + (((long)b*N_ + n)*64 + (c16-12)*16));
    g0 = *(const uint4*)(p); g1 = *(const uint4*)(p+8);
  }
  {
    int gg = c16*2;
    *(uint4*)((char*)sX + b*512 + (((gg  ) ^ (b&7))<<4)) = g0;
    *(uint4*)((char*)sX + b*512 + (((gg+1) ^ (b&7))<<4)) = g1;
  }
  __syncthreads();
  f32x4 acc; 
#pragma unroll
  for (int i=0;i<4;++i) acc[i]=0.f;
  int orow = w*16 + (l&15);
  int arow = l&15;
#pragma unroll
  for (int ks=0; ks<8; ++ks){
    int g = ks*4 + (l>>4);
    short8 a = *(const short8*)((const char*)sX + arow*512 + ((g ^ (arow&7))<<4));
    short8 bb = *(const short8*)((const char*)sW + orow*512 + ((g ^ (orow&7))<<4));
    acc = __builtin_amdgcn_mfma_f32_16x16x32_bf16(a, bb, acc, 0,0,0);
  }
  int o = half*64 + orow;
  float bia = b2f(bg[n*128 + o]);
#pragma unroll
  for (int i=0;i<4;++i){
    int bb2 = (l>>4)*4 + i;
    float v = acc[i] + bia;
    float sg = 1.f/(1.f+__expf(-v));
    long idx = ((long)bb2*N_ + n)*64;
    if (half==0) zbuf[idx + o] = sg;
    else {
      float s0v = st[idx + (o-64)];
      rs[idx + (o-64)] = f2b(sg*s0v);
    }
  }
}

// ---------------- candidate + state update ----------------
__global__ __launch_bounds__(256) void k_cand(
    const float* __restrict__ x, const float* __restrict__ zbuf,
    const unsigned short* __restrict__ AX, const unsigned short* __restrict__ ARS,
    const unsigned short* __restrict__ rs,
    const unsigned short* __restrict__ Wc, const unsigned short* __restrict__ bc,
    float* __restrict__ st, unsigned short* __restrict__ stb,
    unsigned short* __restrict__ inner, int t)
{
  __shared__ __align__(16) unsigned short sW[64*256];
  __shared__ __align__(16) unsigned short sX[16*256];
  int n = blockIdx.x;
  int tid = threadIdx.x, w = tid>>6, l = tid&63;
  const unsigned short* Wsrc = Wc + (long)n*16384;
#pragma unroll
  for (int i=0;i<8;++i){
    int c = (w*8+i)*64 + l;
    gl16((const char*)Wsrc + c*16, (char*)sW + (w*8+i)*1024);
  }
  int b = tid>>4, c16 = tid&15;
  uint4 g0, g1;
  if (c16 < 4){
    const float* p = x + (((long)(b*T_+t)*N_ + n)*64 + c16*16);
    float4 f0 = *(const float4*)(p+0), f1 = *(const float4*)(p+4);
    float4 f2v = *(const float4*)(p+8), f3 = *(const float4*)(p+12);
    g0.x = pk2(f0.x,f0.y); g0.y = pk2(f0.z,f0.w); g0.z = pk2(f1.x,f1.y); g0.w = pk2(f1.z,f1.w);
    g1.x = pk2(f2v.x,f2v.y); g1.y = pk2(f2v.z,f2v.w); g1.z = pk2(f3.x,f3.y); g1.w = pk2(f3.z,f3.w);
  } else {
    const unsigned short* p;
    if (c16<8)       p = rs  + (((long)b*N_ + n)*64 + (c16-4)*16);
    else if (c16<12) p = AX  + (((long)(b*T_+t)*N_ + n)*64 + (c16-8)*16);
    else             p = ARS + (((long)b*N_ + n)*64 + (c16-12)*16);
    g0 = *(const uint4*)(p); g1 = *(const uint4*)(p+8);
  }
  {
    int gg = c16*2;
    *(uint4*)((char*)sX + b*512 + (((gg  ) ^ (b&7))<<4)) = g0;
    *(uint4*)((char*)sX + b*512 + (((gg+1) ^ (b&7))<<4)) = g1;
  }
  __syncthreads();
  f32x4 acc;
#pragma unroll
  for (int i=0;i<4;++i) acc[i]=0.f;
  int orow = w*16 + (l&15);
  int arow = l&15;
#pragma unroll
  for (int ks=0; ks<8; ++ks){
    int g = ks*4 + (l>>4);
    short8 a = *(const short8*)((const char*)sX + arow*512 + ((g ^ (arow&7))<<4));
    short8 bb = *(const short8*)((const char*)sW + orow*512 + ((g ^ (orow&7))<<4));
    acc = __builtin_amdgcn_mfma_f32_16x16x32_bf16(a, bb, acc, 0,0,0);
  }
  float bia = b2f(bc[n*64 + orow]);
#pragma unroll
  for (int i=0;i<4;++i){
    int bb2 = (l>>4)*4 + i;
    float hc = tanhf(acc[i] + bia);
    long idx = ((long)bb2*N_ + n)*64 + orow;
    float zv = zbuf[idx];
    float olds = st[idx];
    float nv = zv*olds + (1.f-zv)*hc;
    st[idx]=nv; stb[idx]=f2b(nv);
    inner[((long)(bb2*T_+t)*N_ + n)*64 + orow] = f2b(nv);
  }
}

// ---------------- post: temporal conv + residual + relu + layernorm ----------------
__global__ __launch_bounds__(256) void k_post(
    const unsigned short* __restrict__ inner, const float* __restrict__ x,
    const unsigned short* __restrict__ Wcat,
    const float* __restrict__ tcb, const float* __restrict__ rcb,
    const float* __restrict__ lng, const float* __restrict__ lnb,
    float* __restrict__ out)
{
  __shared__ __align__(16) unsigned short sF[64*256];
  __shared__ __align__(16) unsigned short sW[64*256];
  int id = blockIdx.x;
  int bt = id>>5, nb = id&31;
  int b = bt/T_, t = bt%T_;
  int n0 = nb*64;
  int tid = threadIdx.x, w = tid>>6, l = tid&63;
#pragma unroll
  for (int i=0;i<8;++i){
    int c = (w*8+i)*64 + l;
    gl16((const char*)Wcat + c*16, (char*)sW + (w*8+i)*1024);
  }
  int row = tid&63, q = tid>>6;
  uint4 ch[8];
  if (q<3){
    int ts = t + q - 1;
    if (ts>=0 && ts<T_){
      const uint4* p = (const uint4*)(inner + (((long)(b*T_+ts)*N_) + n0+row)*64);
#pragma unroll
      for (int hh=0;hh<8;++hh) ch[hh]=p[hh];
    } else {
      uint4 zz; zz.x=0u; zz.y=0u; zz.z=0u; zz.w=0u;
#pragma unroll
      for (int hh=0;hh<8;++hh) ch[hh]=zz;
    }
  } else {
    const float4* p = (const float4*)(x + (((long)bt*N_) + n0+row)*64);
#pragma unroll
    for (int hh=0;hh<8;++hh){
      float4 u0=p[2*hh], u1=p[2*hh+1];
      ch[hh].x=pk2(u0.x,u0.y); ch[hh].y=pk2(u0.z,u0.w);
      ch[hh].z=pk2(u1.x,u1.y); ch[hh].w=pk2(u1.z,u1.w);
    }
  }
#pragma unroll
  for (int hh=0;hh<8;++hh){
    int g = q*8+hh;
    *(uint4*)((char*)sF + row*512 + ((g ^ (row&7))<<4)) = ch[hh];
  }
  __syncthreads();
  f32x4 acc[4];
#pragma unroll
  for (int ot=0; ot<4; ++ot)
#pragma unroll
    for (int i=0;i<4;++i) acc[ot][i]=0.f;
  int arow = w*16 + (l&15);
#pragma unroll
  for (int ks=0; ks<8; ++ks){
    int g = ks*4 + (l>>4);
    short8 a = *(const short8*)((const char*)sF + arow*512 + ((g ^ (arow&7))<<4));
#pragma unroll
    for (int ot=0; ot<4; ++ot){
      int o = ot*16 + (l&15);
      short8 bb = *(const short8*)((const char*)sW + o*512 + ((g ^ (o&7))<<4));
      acc[ot] = __builtin_amdgcn_mfma_f32_16x16x32_bf16(a, bb, acc[ot], 0,0,0);
    }
  }
  float s1[4]={0.f,0.f,0.f,0.f}, s2[4]={0.f,0.f,0.f,0.f};
#pragma unroll
  for (int ot=0; ot<4; ++ot){
    int o = ot*16 + (l&15);
    float bia = tcb[o] + rcb[o];
#pragma unroll
    for (int i=0;i<4;++i){
      float v = fmaxf(acc[ot][i] + bia, 0.f);
      acc[ot][i] = v;
      s1[i]+=v; s2[i]+=v*v;
    }
  }
#pragma unroll
  for (int msk=1; msk<16; msk<<=1){
#pragma unroll
    for (int i=0;i<4;++i){
      s1[i] += __shfl_xor(s1[i], msk, 64);
      s2[i] += __shfl_xor(s2[i], msk, 64);
    }
  }
#pragma unroll
  for (int i=0;i<4;++i){
    float mu = s1[i]*(1.f/64.f);
    float var = s2[i]*(1.f/64.f) - mu*mu;
    float rstd = rsqrtf(fmaxf(var,0.f)+1e-5f);
    int rr = n0 + w*16 + (l>>4)*4 + i;
#pragma unroll
    for (int ot=0; ot<4; ++ot){
      int o = ot*16 + (l&15);
      out[(((long)bt*N_) + rr)*64 + o] = (acc[ot][i]-mu)*rstd*lng[o] + lnb[o];
    }
  }
}

// ---------------- launch ----------------
extern "C" void kernel_launch(void* const* d_in, const int* in_sizes, int n_in,
                              void* d_out, int out_size, void* d_ws, size_t ws_size,
                              hipStream_t stream)
{
  const float* x    = (const float*)d_in[0];
  const float* init = (const float*)d_in[1];
  const float* E    = (const float*)d_in[2];
  const float* gW   = (const float*)d_in[3];
  const float* asrc = (const float*)d_in[4];
  const float* adst = (const float*)d_in[5];
  const float* wpg  = (const float*)d_in[6];
  const float* bpg  = (const float*)d_in[7];
  const float* wpc  = (const float*)d_in[8];
  const float* bpc  = (const float*)d_in[9];
  const float* tcw  = (const float*)d_in[10];
  const float* tcb  = (const float*)d_in[11];
  const float* rcw  = (const float*)d_in[12];
  const float* rcb  = (const float*)d_in[13];
  const float* lng  = (const float*)d_in[14];
  const float* lnb  = (const float*)d_in[15];
  float* out = (float*)d_out;

  char* p = (char*)d_ws;
  auto alloc = [&](size_t bytes)->char*{ char* r = p; p += (bytes + 255) & ~(size_t)255; return r; };
  unsigned short* Abf  = (unsigned short*)alloc((size_t)N_*N_*2);
  unsigned short* Wg   = (unsigned short*)alloc((size_t)N_*32768*2);
  unsigned short* Wc   = (unsigned short*)alloc((size_t)N_*16384*2);
  unsigned short* bg   = (unsigned short*)alloc((size_t)N_*128*2);
  unsigned short* bc   = (unsigned short*)alloc((size_t)N_*64*2);
  unsigned short* AX   = (unsigned short*)alloc((size_t)B_*T_*N_*64*2);
  unsigned short* AS   = (unsigned short*)alloc((size_t)B_*N_*64*2);
  unsigned short* ARS  = (unsigned short*)alloc((size_t)B_*N_*64*2);
  unsigned short* rsb  = (unsigned short*)alloc((size_t)B_*N_*64*2);
  unsigned short* stb  = (unsigned short*)alloc((size_t)B_*N_*64*2);
  unsigned short* inner= (unsigned short*)alloc((size_t)B_*T_*N_*64*2);
  unsigned short* Wcat = (unsigned short*)alloc((size_t)64*256*2);
  float* sArr = (float*)alloc((size_t)NH_*N_*4);
  float* dArr = (float*)alloc((size_t)NH_*N_*4);
  float* dmax = (float*)alloc((size_t)NH_*4);
  float* denom= (float*)alloc((size_t)NH_*N_*4);
  float* stf  = (float*)alloc((size_t)B_*N_*64*4);
  float* zbuf = (float*)alloc((size_t)B_*N_*64*4);

  k_gat_sd<<<32,256,0,stream>>>(E,gW,asrc,adst,sArr,dArr);
  k_dmax<<<4,256,0,stream>>>(dArr,dmax);
  k_denom<<<dim3(N_,NH_),256,0,stream>>>(sArr,dArr,dmax,denom);
  k_adj<<<N_,256,0,stream>>>(sArr,dArr,dmax,denom,Abf);
  k_nalw<<<dim3(128,4),256,0,stream>>>(E,wpg,Wg,128);
  k_nalw<<<dim3(64,4),256,0,stream>>>(E,wpc,Wc,64);
  k_nalb<<<1536,256,0,stream>>>(E,bpg,bpc,bg,bc);
  k_wcat<<<64,256,0,stream>>>(tcw,rcw,Wcat);
  k_init<<<(B_*N_*64)/256,256,0,stream>>>(init,stf,stb);

  // AX[b][t] = A @ x[b][t]  for all (b,t): 96 z-blocks of two 64-col panels
  k_gemm<128,128,true><<<dim3(16,96),256,0,stream>>>(Abf,
      (const char*)x,          2L*N_*64*4,
      (const char*)(x + N_*64),2L*N_*64*4,
      AX,          2L*N_*64,
      AX + N_*64,  2L*N_*64);

  for (int t=0; t<T_; ++t){
    k_gemm<64,64,false><<<dim3(32,16),256,0,stream>>>(Abf,
        (const char*)stb, (long)N_*64*2, (const char*)0, 0,
        AS, (long)N_*64, (unsigned short*)0, 0);
    k_gates<<<dim3(N_,2),256,0,stream>>>(x,stf,AX,AS,Wg,bg,zbuf,rsb,t);
    k_gemm<64,64,false><<<dim3(32,16),256,0,stream>>>(Abf,
        (const char*)rsb, (long)N_*64*2, (const char*)0, 0,
        ARS, (long)N_*64, (unsigned short*)0, 0);
    k_cand<<<N_,256,0,stream>>>(x,zbuf,AX,ARS,rsb,Wc,bc,stf,stb,inner,t);
  }

  k_post<<<B_*T_*32,256,0,stream>>>(inner,x,Wcat,tcb,rcb,lng,lnb,out);
  hipMemcpyAsync(out + (size_t)B_*T_*N_*64, stf, (size_t)B_*N_*64*4,
                 hipMemcpyDeviceToDevice, stream);
}